// Round 5
// baseline (46.449 us; speedup 1.0000x reference)
//
#include <hip/hip_runtime.h>

namespace {

constexpr int CH  = 8;     // hidden/out channels
constexpr int CIN = 8;     // feature channels
constexpr int HH  = 100;
constexpr int WW  = 136;
constexpr int HW  = HH * WW;   // 13600
constexpr int NP  = 232;       // params per instance
constexpr int VP  = 4;         // pixels per thread (float4)
constexpr int BLK = 256;

typedef float f32x4 __attribute__((ext_vector_type(4)));

// param layout per instance:
//  w1[o][i] = p[o*10 + i]        o<8, i<10  (i=0: rel_x, i=1: rel_y, i=2+c: feat c)
//  w2[o][i] = p[80  + o*8 + i]
//  w3[o][i] = p[144 + o*8 + i]
//  b1[o]=p[208+o]  b2[o]=p[216+o]  b3[o]=p[224+o]

__global__ __launch_bounds__(BLK)
void dmh_kernel(const float* __restrict__ feats,     // (N_IMG, CIN, HW)
                const float* __restrict__ params,    // (n_inst, NP)
                const float* __restrict__ ilocs,     // (n_inst, 2)
                const int*   __restrict__ im_inds,   // (n_inst)
                const int*   __restrict__ lvls,      // (n_inst)
                const int*   __restrict__ stride_p,  // (1)
                float*       __restrict__ out)       // (n_inst, CH, HW)
{
    const int n   = blockIdx.y;
    const int tid = threadIdx.x;

    // all params wave-uniform -> scalar loads through constant cache (no LDS)
    const float* __restrict__ p = params + (size_t)n * NP;

    const int p0 = (blockIdx.x * BLK + tid) * VP;
    if (p0 >= HW) return;

    // per-instance uniforms (all s_load)
    const int   im  = im_inds[n];
    const int   lvl = lvls[n];
    const float soi_tab[5] = {64.f, 128.f, 256.f, 512.f, 1024.f};
    const float inv_soi = 1.0f / soi_tab[lvl];
    const float ix = ilocs[2 * n + 0];
    const float iy = ilocs[2 * n + 1];

    // stride scalar: tolerate int32 or float32 encoding
    const int   s_i = stride_p[0];
    const float fs  = (s_i >= 1 && s_i <= 65536) ? (float)s_i : __int_as_float(s_i);
    const float fh  = floorf(fs * 0.5f);   // stride // 2

    // load 8 feature channels x 4 pixels (float4, coalesced; L2-resident)
    float f[CIN][VP];
    const float* fbase = feats + (size_t)im * CIN * HW + p0;
    #pragma unroll
    for (int c = 0; c < CIN; ++c) {
        const f32x4 v = *reinterpret_cast<const f32x4*>(fbase + c * HW);
        f[c][0] = v.x; f[c][1] = v.y; f[c][2] = v.z; f[c][3] = v.w;
    }

    // relative coordinates
    float relx[VP], rely[VP];
    #pragma unroll
    for (int j = 0; j < VP; ++j) {
        const int pp = p0 + j;
        const int y  = pp / WW;
        const int x  = pp - y * WW;
        relx[j] = (ix - ((float)x * fs + fh)) * inv_soi;
        rely[j] = (iy - ((float)y * fs + fh)) * inv_soi;
    }

    // layer 1: 10 -> 8, ReLU (weights are SGPR operands directly)
    float h1[CH][VP];
    #pragma unroll
    for (int o = 0; o < CH; ++o) {
        #pragma unroll
        for (int j = 0; j < VP; ++j) {
            float a = fmaf(p[o * 10 + 0], relx[j],
                      fmaf(p[o * 10 + 1], rely[j], p[208 + o]));
            #pragma unroll
            for (int c = 0; c < CIN; ++c)
                a = fmaf(p[o * 10 + 2 + c], f[c][j], a);
            h1[o][j] = fmaxf(a, 0.f);
        }
    }

    // layer 2: 8 -> 8, ReLU
    float h2[CH][VP];
    #pragma unroll
    for (int o = 0; o < CH; ++o) {
        #pragma unroll
        for (int j = 0; j < VP; ++j) {
            float a = p[216 + o];
            #pragma unroll
            for (int i = 0; i < CH; ++i)
                a = fmaf(p[80 + o * 8 + i], h1[i][j], a);
            h2[o][j] = fmaxf(a, 0.f);
        }
    }

    // layer 3: 8 -> 8, ReLU + plain coalesced store
    float* ob = out + (size_t)n * CH * HW + p0;
    #pragma unroll
    for (int o = 0; o < CH; ++o) {
        float r[VP];
        #pragma unroll
        for (int j = 0; j < VP; ++j) {
            float a = p[224 + o];
            #pragma unroll
            for (int i = 0; i < CH; ++i)
                a = fmaf(p[144 + o * 8 + i], h2[i][j], a);
            r[j] = fmaxf(a, 0.f);
        }
        f32x4 v;
        v.x = r[0]; v.y = r[1]; v.z = r[2]; v.w = r[3];
        *reinterpret_cast<f32x4*>(ob + o * HW) = v;
    }
}

} // namespace

extern "C" void kernel_launch(void* const* d_in, const int* in_sizes, int n_in,
                              void* d_out, int out_size, void* d_ws, size_t ws_size,
                              hipStream_t stream) {
    const float* feats  = (const float*)d_in[0];
    const float* params = (const float*)d_in[1];
    const float* ilocs  = (const float*)d_in[2];
    const int*   im     = (const int*)d_in[3];
    const int*   lv     = (const int*)d_in[4];
    const int*   st     = (const int*)d_in[5];
    float*       out    = (float*)d_out;

    const int n_inst = in_sizes[1] / NP;   // 400
    dim3 grid((HW + BLK * VP - 1) / (BLK * VP), n_inst);
    dmh_kernel<<<grid, BLK, 0, stream>>>(feats, params, ilocs, im, lv, st, out);
}

// Round 7
// 38.208 us; speedup vs baseline: 1.2157x; 1.2157x over previous
//
#include <hip/hip_runtime.h>

namespace {

constexpr int CH  = 8;     // hidden/out channels
constexpr int CIN = 8;     // feature channels
constexpr int HH  = 100;
constexpr int WW  = 136;
constexpr int HW  = HH * WW;   // 13600
constexpr int NP  = 232;       // params per instance
constexpr int VP  = 4;         // pixels per thread (float4)
constexpr int BLK = 256;

typedef float f32x4 __attribute__((ext_vector_type(4)));
typedef float f32x2 __attribute__((ext_vector_type(2)));

// source param layout per instance (flat 232):
//  w1[o][i] = p[o*10 + i]   o<8, i<10  (i=0: rel_x, i=1: rel_y, i=2+c: feat c)
//  w2[o][i] = p[80  + o*8 + i]
//  w3[o][i] = p[144 + o*8 + i]
//  b1[o]=p[208+o]  b2[o]=p[216+o]  b3[o]=p[224+o]
//
// LDS layout (padded for 16B-aligned vector reads):
//  sw1[o*12 + i] = w1[o][i]   (stride 12 floats = 48B, 16B aligned)
//  sr [o*8 + i]  = w2[o][i]
//  sr [64 + o*8 + i] = w3[o][i]
//  sr [128+o]=b1, sr[136+o]=b2, sr[144+o]=b3

__global__ __launch_bounds__(BLK)
void dmh_kernel(const float* __restrict__ feats,     // (N_IMG, CIN, HW)
                const float* __restrict__ params,    // (n_inst, NP)
                const float* __restrict__ ilocs,     // (n_inst, 2)
                const int*   __restrict__ im_inds,   // (n_inst)
                const int*   __restrict__ lvls,      // (n_inst)
                const int*   __restrict__ stride_p,  // (1)
                float*       __restrict__ out)       // (n_inst, CH, HW)
{
    const int n   = blockIdx.y;
    const int tid = threadIdx.x;

    __shared__ __attribute__((aligned(16))) float sw1[96];   // 8 x 12
    __shared__ __attribute__((aligned(16))) float sr[152];   // w2(64) w3(64) b(24)

    if (tid < NP) {
        const float v = params[(size_t)n * NP + tid];
        if (tid < 80) {
            const int o = tid / 10, i = tid - o * 10;
            sw1[o * 12 + i] = v;
        } else {
            sr[tid - 80] = v;
        }
    }
    __syncthreads();

    const int p0 = (blockIdx.x * BLK + tid) * VP;
    if (p0 >= HW) return;

    // per-instance uniforms
    const int   im  = im_inds[n];
    const int   lvl = lvls[n];
    const float soi_tab[5] = {64.f, 128.f, 256.f, 512.f, 1024.f};
    const float inv_soi = 1.0f / soi_tab[lvl];
    const float ix = ilocs[2 * n + 0];
    const float iy = ilocs[2 * n + 1];

    // stride scalar: tolerate int32 or float32 encoding
    const int   s_i = stride_p[0];
    const float fs  = (s_i >= 1 && s_i <= 65536) ? (float)s_i : __int_as_float(s_i);
    const float fh  = floorf(fs * 0.5f);   // stride // 2

    // load 8 feature channels x 4 pixels (float4, coalesced; L2-resident)
    float f[CIN][VP];
    const float* fbase = feats + (size_t)im * CIN * HW + p0;
    #pragma unroll
    for (int c = 0; c < CIN; ++c) {
        const f32x4 v = *reinterpret_cast<const f32x4*>(fbase + c * HW);
        f[c][0] = v.x; f[c][1] = v.y; f[c][2] = v.z; f[c][3] = v.w;
    }

    // relative coordinates
    float relx[VP], rely[VP];
    #pragma unroll
    for (int j = 0; j < VP; ++j) {
        const int pp = p0 + j;
        const int y  = pp / WW;
        const int x  = pp - y * WW;
        relx[j] = (ix - ((float)x * fs + fh)) * inv_soi;
        rely[j] = (iy - ((float)y * fs + fh)) * inv_soi;
    }

    // layer 1: 10 -> 8, ReLU  (weights via 2x b128 + 1x b64 per row)
    float h1[CH][VP];
    #pragma unroll
    for (int o = 0; o < CH; ++o) {
        const f32x4 a0 = *reinterpret_cast<const f32x4*>(&sw1[o * 12]);
        const f32x4 a1 = *reinterpret_cast<const f32x4*>(&sw1[o * 12 + 4]);
        const f32x2 a2 = *reinterpret_cast<const f32x2*>(&sw1[o * 12 + 8]);
        const float b  = sr[128 + o];
        #pragma unroll
        for (int j = 0; j < VP; ++j) {
            float a = fmaf(a0.x, relx[j], fmaf(a0.y, rely[j], b));
            a = fmaf(a0.z, f[0][j], a);
            a = fmaf(a0.w, f[1][j], a);
            a = fmaf(a1.x, f[2][j], a);
            a = fmaf(a1.y, f[3][j], a);
            a = fmaf(a1.z, f[4][j], a);
            a = fmaf(a1.w, f[5][j], a);
            a = fmaf(a2.x, f[6][j], a);
            a = fmaf(a2.y, f[7][j], a);
            h1[o][j] = fmaxf(a, 0.f);
        }
    }

    // layer 2: 8 -> 8, ReLU  (2x b128 per row)
    float h2[CH][VP];
    #pragma unroll
    for (int o = 0; o < CH; ++o) {
        const f32x4 w0 = *reinterpret_cast<const f32x4*>(&sr[o * 8]);
        const f32x4 w1 = *reinterpret_cast<const f32x4*>(&sr[o * 8 + 4]);
        const float b  = sr[136 + o];
        #pragma unroll
        for (int j = 0; j < VP; ++j) {
            float a = b;
            a = fmaf(w0.x, h1[0][j], a);
            a = fmaf(w0.y, h1[1][j], a);
            a = fmaf(w0.z, h1[2][j], a);
            a = fmaf(w0.w, h1[3][j], a);
            a = fmaf(w1.x, h1[4][j], a);
            a = fmaf(w1.y, h1[5][j], a);
            a = fmaf(w1.z, h1[6][j], a);
            a = fmaf(w1.w, h1[7][j], a);
            h2[o][j] = fmaxf(a, 0.f);
        }
    }

    // layer 3: 8 -> 8, ReLU + coalesced float4 store
    float* ob = out + (size_t)n * CH * HW + p0;
    #pragma unroll
    for (int o = 0; o < CH; ++o) {
        const f32x4 w0 = *reinterpret_cast<const f32x4*>(&sr[64 + o * 8]);
        const f32x4 w1 = *reinterpret_cast<const f32x4*>(&sr[64 + o * 8 + 4]);
        const float b  = sr[144 + o];
        float r[VP];
        #pragma unroll
        for (int j = 0; j < VP; ++j) {
            float a = b;
            a = fmaf(w0.x, h2[0][j], a);
            a = fmaf(w0.y, h2[1][j], a);
            a = fmaf(w0.z, h2[2][j], a);
            a = fmaf(w0.w, h2[3][j], a);
            a = fmaf(w1.x, h2[4][j], a);
            a = fmaf(w1.y, h2[5][j], a);
            a = fmaf(w1.z, h2[6][j], a);
            a = fmaf(w1.w, h2[7][j], a);
            r[j] = fmaxf(a, 0.f);
        }
        f32x4 v;
        v.x = r[0]; v.y = r[1]; v.z = r[2]; v.w = r[3];
        *reinterpret_cast<f32x4*>(ob + o * HW) = v;
    }
}

} // namespace

extern "C" void kernel_launch(void* const* d_in, const int* in_sizes, int n_in,
                              void* d_out, int out_size, void* d_ws, size_t ws_size,
                              hipStream_t stream) {
    const float* feats  = (const float*)d_in[0];
    const float* params = (const float*)d_in[1];
    const float* ilocs  = (const float*)d_in[2];
    const int*   im     = (const int*)d_in[3];
    const int*   lv     = (const int*)d_in[4];
    const int*   st     = (const int*)d_in[5];
    float*       out    = (float*)d_out;

    const int n_inst = in_sizes[1] / NP;   // 400
    dim3 grid((HW + BLK * VP - 1) / (BLK * VP), n_inst);
    dmh_kernel<<<grid, BLK, 0, stream>>>(feats, params, ilocs, im, lv, st, out);
}